// Round 1
// baseline (764.928 us; speedup 1.0000x reference)
//
#include <hip/hip_runtime.h>

#define HH 512
#define WW 512
#define BB 4
#define SH 64
#define SW 64
#define NPRE 128
#define LAMV 0.24f
#define EPSV 1e-8f

// ---------------- prep: cv / ch edge weights ----------------
__global__ __launch_bounds__(256) void prep_kernel(
    const float* __restrict__ image, const float* __restrict__ ybic,
    const float* __restrict__ logk,
    float* __restrict__ cv, float* __restrict__ ch)
{
    int idx = blockIdx.x * 256 + threadIdx.x;
    if (idx >= BB * HH * WW) return;
    int x = idx % WW;
    int y = (idx / WW) % HH;
    int b = idx / (WW * HH);

    float K = expf(logk[0]);
    float invK2 = 1.0f / (K * K);

    const float* img = image + (size_t)b * 3 * HH * WW;
    const float* yb  = ybic  + (size_t)b * HH * WW;

    float f0 = img[y * WW + x];
    float f1 = img[HH * WW + y * WW + x];
    float f2 = img[2 * HH * WW + y * WW + x];
    float f3 = yb[y * WW + x];

    if (y < HH - 1) {
        float s = fabsf(img[(y + 1) * WW + x] - f0)
                + fabsf(img[HH * WW + (y + 1) * WW + x] - f1)
                + fabsf(img[2 * HH * WW + (y + 1) * WW + x] - f2)
                + fabsf(yb[(y + 1) * WW + x] - f3);
        s *= 0.25f;
        cv[(size_t)b * (HH - 1) * WW + y * WW + x] = 1.0f / (1.0f + s * s * invK2);
    }
    if (x < WW - 1) {
        float s = fabsf(img[y * WW + x + 1] - f0)
                + fabsf(img[HH * WW + y * WW + x + 1] - f1)
                + fabsf(img[2 * HH * WW + y * WW + x + 1] - f2)
                + fabsf(yb[y * WW + x + 1] - f3);
        s *= 0.25f;
        ch[(size_t)b * HH * (WW - 1) + y * (WW - 1) + x] = 1.0f / (1.0f + s * s * invK2);
    }
}

// ---------------- fused step: diffuse + block-mean + adjust ----------------
// Grid: (WW/64, HH/64, BB), block 256. Thread = 4x4 pixels.
// tx in [0,16), ty in [0,16); pixel base (tileY*64+ty*4, tileX*64+tx*4).
// One 8x8 downsample block == 2x2 thread group (lanes t, t^1, t^16, t^17 - same wave).
__global__ __launch_bounds__(256) void step_kernel(
    const float* __restrict__ Iin, float* __restrict__ Iout,
    const float* __restrict__ cv, const float* __restrict__ ch,
    const float* __restrict__ src, const float* __restrict__ mask)
{
    const int b = blockIdx.z;
    const int tileX = blockIdx.x, tileY = blockIdx.y;
    const int tx = threadIdx.x & 15, ty = threadIdx.x >> 4;
    const int gx  = tileX * 64 + tx * 4;
    const int gy0 = tileY * 64 + ty * 4;

    const float* I   = Iin + (size_t)b * HH * WW;
    const float* cvb = cv  + (size_t)b * (HH - 1) * WW;
    const float* chb = ch  + (size_t)b * HH * (WW - 1);

    float nv[4][4];
    float s = 0.0f;

    #pragma unroll
    for (int r = 0; r < 4; ++r) {
        const int y = gy0 + r;
        const float* row = I + (size_t)y * WW;

        float4 c  = *(const float4*)(row + gx);
        float  lf = (gx > 0)       ? row[gx - 1] : 0.0f;
        float  rt = (gx + 4 < WW)  ? row[gx + 4] : 0.0f;
        float4 up = (y > 0)        ? *(const float4*)(row - WW + gx) : make_float4(0, 0, 0, 0);
        float4 dn = (y < HH - 1)   ? *(const float4*)(row + WW + gx) : make_float4(0, 0, 0, 0);
        float4 cy = (y < HH - 1)   ? *(const float4*)(cvb + (size_t)y * WW + gx) : make_float4(0, 0, 0, 0);
        float4 cm = (y > 0)        ? *(const float4*)(cvb + (size_t)(y - 1) * WW + gx) : make_float4(0, 0, 0, 0);

        const float* chrow = chb + (size_t)y * (WW - 1);
        float chv[5];
        #pragma unroll
        for (int j = 0; j < 5; ++j) {
            int xx = gx - 1 + j;
            chv[j] = (xx >= 0 && xx < WW - 1) ? chrow[xx] : 0.0f;
        }

        float cc[4] = {c.x, c.y, c.z, c.w};
        float uu[4] = {up.x, up.y, up.z, up.w};
        float dd[4] = {dn.x, dn.y, dn.z, dn.w};
        float cyv[4] = {cy.x, cy.y, cy.z, cy.w};
        float cmv[4] = {cm.x, cm.y, cm.z, cm.w};

        #pragma unroll
        for (int j = 0; j < 4; ++j) {
            float left  = j ? cc[j - 1] : lf;
            float right = (j < 3) ? cc[j + 1] : rt;
            float v = cc[j] + LAMV * ( cyv[j]    * (dd[j] - cc[j])
                                     - cmv[j]    * (cc[j] - uu[j])
                                     + chv[j + 1] * (right - cc[j])
                                     - chv[j]    * (cc[j] - left) );
            nv[r][j] = v;
            s += v;
        }
    }

    // reduce over the 2x2 thread group -> sum of the 8x8 block (64 px)
    s += __shfl_xor(s, 1);
    s += __shfl_xor(s, 16);
    float mean = s * (1.0f / 64.0f);

    const int sbx = tileX * 8 + (tx >> 1);
    const int sby = tileY * 8 + (ty >> 1);
    const size_t sidx = (size_t)b * SH * SW + (size_t)sby * SW + sbx;
    float mv = mask[sidx];
    float sv = src[sidx];
    float ratio = (mv < 0.5f) ? 1.0f : sv / (mean + EPSV);

    float* O = Iout + (size_t)b * HH * WW;
    #pragma unroll
    for (int r = 0; r < 4; ++r) {
        const int y = gy0 + r;
        float4 o = make_float4(nv[r][0] * ratio, nv[r][1] * ratio,
                               nv[r][2] * ratio, nv[r][3] * ratio);
        *(float4*)(O + (size_t)y * WW + gx) = o;
    }
}

extern "C" void kernel_launch(void* const* d_in, const int* in_sizes, int n_in,
                              void* d_out, int out_size, void* d_ws, size_t ws_size,
                              hipStream_t stream) {
    const float* image  = (const float*)d_in[0];
    const float* source = (const float*)d_in[1];
    const float* mask   = (const float*)d_in[2];
    const float* ybic   = (const float*)d_in[3];
    const float* logk   = (const float*)d_in[4];

    float* out_img = (float*)d_out;                          // [B,1,H,W]
    float* out_cv  = out_img + (size_t)BB * HH * WW;         // [B,1,H-1,W]
    float* out_ch  = out_cv + (size_t)BB * (HH - 1) * WW;    // [B,1,W-1 per row]
    float* ws      = (float*)d_ws;                           // 4 MB ping buffer

    // cv / ch straight into their output slots; read from there each iter.
    int total = BB * HH * WW;
    prep_kernel<<<(total + 255) / 256, 256, 0, stream>>>(image, ybic, logk, out_cv, out_ch);

    dim3 grid(WW / 64, HH / 64, BB);
    const float* cur = ybic;  // iteration 0 reads y_bicubic directly
    for (int i = 0; i < NPRE; ++i) {
        float* dst = (i % 2 == 0) ? ws : out_img;  // i=127 (odd) -> out_img
        step_kernel<<<grid, 256, 0, stream>>>(cur, dst, out_cv, out_ch, source, mask);
        cur = dst;
    }
}

// Round 2
// 633.797 us; speedup vs baseline: 1.2069x; 1.2069x over previous
//
#include <hip/hip_runtime.h>

#define HH 512
#define WW 512
#define BB 4
#define SH 64
#define SW 64
#define NPRE 128
#define T_ITERS 4
#define NLAUNCH (NPRE / T_ITERS)
#define LAMV 0.24f
#define EPSV 1e-8f

// ---------------- prep: cv / ch edge weights (unchanged, verified) ----------------
__global__ __launch_bounds__(256) void prep_kernel(
    const float* __restrict__ image, const float* __restrict__ ybic,
    const float* __restrict__ logk,
    float* __restrict__ cv, float* __restrict__ ch)
{
    int idx = blockIdx.x * 256 + threadIdx.x;
    if (idx >= BB * HH * WW) return;
    int x = idx % WW;
    int y = (idx / WW) % HH;
    int b = idx / (WW * HH);

    float K = expf(logk[0]);
    float invK2 = 1.0f / (K * K);

    const float* img = image + (size_t)b * 3 * HH * WW;
    const float* yb  = ybic  + (size_t)b * HH * WW;

    float f0 = img[y * WW + x];
    float f1 = img[HH * WW + y * WW + x];
    float f2 = img[2 * HH * WW + y * WW + x];
    float f3 = yb[y * WW + x];

    if (y < HH - 1) {
        float s = fabsf(img[(y + 1) * WW + x] - f0)
                + fabsf(img[HH * WW + (y + 1) * WW + x] - f1)
                + fabsf(img[2 * HH * WW + (y + 1) * WW + x] - f2)
                + fabsf(yb[(y + 1) * WW + x] - f3);
        s *= 0.25f;
        cv[(size_t)b * (HH - 1) * WW + y * WW + x] = 1.0f / (1.0f + s * s * invK2);
    }
    if (x < WW - 1) {
        float s = fabsf(img[y * WW + x + 1] - f0)
                + fabsf(img[HH * WW + y * WW + x + 1] - f1)
                + fabsf(img[2 * HH * WW + y * WW + x + 1] - f2)
                + fabsf(yb[y * WW + x + 1] - f3);
        s *= 0.25f;
        ch[(size_t)b * HH * (WW - 1) + y * (WW - 1) + x] = 1.0f / (1.0f + s * s * invK2);
    }
}

// ---------------- multi-step: 4 fused iterations per launch ----------------
// Grid (8,8,4), 256 threads. WG owns valid 64x64 tile; computes over a 128x128
// region (32 px halo). Thread = one absolute 8x8 block; 16x16 blocks per region.
// I and cv/ch coefficients live in registers; halo via LDS edge buffers.
// At in-kernel iter k, a block is computed iff its block-distance to every
// non-image region edge is >= k+1 (contamination = 1 block ring / iter).
__global__ __launch_bounds__(256, 1) void multi_step_kernel(
    const float* __restrict__ Iin, float* __restrict__ Iout,
    const float* __restrict__ cv, const float* __restrict__ ch,
    const float* __restrict__ src, const float* __restrict__ mask)
{
    const int b = blockIdx.z;
    const int tileX = blockIdx.x, tileY = blockIdx.y;
    const int tid = threadIdx.x;
    const int bx = tid & 15, by = tid >> 4;

    const int aY = tileY * 64 - 32 + by * 8;   // absolute block origin
    const int aX = tileX * 64 - 32 + bx * 8;
    const bool inImg = (aY >= 0) && (aY < HH) && (aX >= 0) && (aX < WW);

    const int dL = (tileX > 0) ? bx        : 99;
    const int dR = (tileX < 7) ? (15 - bx) : 99;
    const int dT = (tileY > 0) ? by        : 99;
    const int dB = (tileY < 7) ? (15 - by) : 99;
    const int minD = min(min(dL, dR), min(dT, dB));

    const float* Ib  = Iin  + (size_t)b * HH * WW;
    float*       Ob  = Iout + (size_t)b * HH * WW;
    const float* cvb = cv   + (size_t)b * (HH - 1) * WW;
    const float* chb = ch   + (size_t)b * HH * (WW - 1);

    float I[8][8];
    float cvr[9][8];   // vertical-interface coeff, interfaces aY-1 .. aY+7
    float chr[8][9];   // horizontal-interface coeff, interfaces aX-1 .. aX+7
    float sv = 0.0f, mv = 0.0f;

    if (inImg) {
        #pragma unroll
        for (int r = 0; r < 8; ++r) {
            const float* row = Ib + (size_t)(aY + r) * WW + aX;
            float4 p0 = *(const float4*)(row);
            float4 p1 = *(const float4*)(row + 4);
            I[r][0] = p0.x; I[r][1] = p0.y; I[r][2] = p0.z; I[r][3] = p0.w;
            I[r][4] = p1.x; I[r][5] = p1.y; I[r][6] = p1.z; I[r][7] = p1.w;
        }
        #pragma unroll
        for (int i = 0; i < 9; ++i) {
            int y = aY - 1 + i;
            if (y >= 0 && y < HH - 1) {
                const float* row = cvb + (size_t)y * WW + aX;
                float4 p0 = *(const float4*)(row);
                float4 p1 = *(const float4*)(row + 4);
                cvr[i][0] = p0.x; cvr[i][1] = p0.y; cvr[i][2] = p0.z; cvr[i][3] = p0.w;
                cvr[i][4] = p1.x; cvr[i][5] = p1.y; cvr[i][6] = p1.z; cvr[i][7] = p1.w;
            } else {
                #pragma unroll
                for (int c = 0; c < 8; ++c) cvr[i][c] = 0.0f;
            }
        }
        #pragma unroll
        for (int r = 0; r < 8; ++r) {
            const float* row = chb + (size_t)(aY + r) * (WW - 1);
            #pragma unroll
            for (int j = 0; j < 9; ++j) {
                int x = aX - 1 + j;
                chr[r][j] = ((unsigned)x <= (unsigned)(WW - 2)) ? row[x] : 0.0f;
            }
        }
        const size_t sidx = (size_t)b * SH * SW + (size_t)(aY >> 3) * SW + (aX >> 3);
        sv = src[sidx];
        mv = mask[sidx];
    } else {
        #pragma unroll
        for (int r = 0; r < 8; ++r)
            #pragma unroll
            for (int c = 0; c < 8; ++c) I[r][c] = 0.0f;
    }
    const bool useR = (mv >= 0.5f);

    // Edge buffers, [elem][block] layout => stride-1 across threads (bank-conflict-free)
    __shared__ float eTop[8][256];
    __shared__ float eBot[8][256];
    __shared__ float eLft[8][256];
    __shared__ float eRgt[8][256];

    for (int k = 0; k < T_ITERS; ++k) {
        // publish current edges (all threads; out-of-image threads publish zeros)
        #pragma unroll
        for (int c = 0; c < 8; ++c) {
            eTop[c][tid] = I[0][c];
            eBot[c][tid] = I[7][c];
            eLft[c][tid] = I[c][0];
            eRgt[c][tid] = I[c][7];
        }
        __syncthreads();

        const bool active = inImg && (minD > k);
        if (active) {
            const int nUp = tid - 16, nDn = tid + 16, nLf = tid - 1, nRg = tid + 1;
            float prev[8];   // old values of row r-1
            float newr[8];
            float s = 0.0f;
            #pragma unroll
            for (int r = 0; r < 8; ++r) {
                #pragma unroll
                for (int c = 0; c < 8; ++c) {
                    const float v  = I[r][c];
                    const float up = (r > 0) ? prev[c]      : eBot[c][nUp];
                    const float dn = (r < 7) ? I[r + 1][c]  : eTop[c][nDn];
                    const float lf = (c > 0) ? I[r][c - 1]  : eRgt[r][nLf];
                    const float rg = (c < 7) ? I[r][c + 1]  : eLft[r][nRg];
                    const float nv = v + LAMV * ( cvr[r + 1][c] * (dn - v)
                                                - cvr[r][c]     * (v - up)
                                                + chr[r][c + 1] * (rg - v)
                                                - chr[r][c]     * (v - lf) );
                    newr[c] = nv;
                    s += nv;
                }
                #pragma unroll
                for (int c = 0; c < 8; ++c) {
                    prev[c] = I[r][c];
                    I[r][c] = newr[c];
                }
            }
            const float mean  = s * (1.0f / 64.0f);
            const float ratio = useR ? (sv / (mean + EPSV)) : 1.0f;
            #pragma unroll
            for (int r = 0; r < 8; ++r)
                #pragma unroll
                for (int c = 0; c < 8; ++c) I[r][c] *= ratio;
        }
        __syncthreads();
    }

    // store the valid 64x64 tile (central blocks only)
    if (inImg && minD >= T_ITERS) {
        #pragma unroll
        for (int r = 0; r < 8; ++r) {
            float* row = Ob + (size_t)(aY + r) * WW + aX;
            float4 p0 = make_float4(I[r][0], I[r][1], I[r][2], I[r][3]);
            float4 p1 = make_float4(I[r][4], I[r][5], I[r][6], I[r][7]);
            *(float4*)(row)     = p0;
            *(float4*)(row + 4) = p1;
        }
    }
}

extern "C" void kernel_launch(void* const* d_in, const int* in_sizes, int n_in,
                              void* d_out, int out_size, void* d_ws, size_t ws_size,
                              hipStream_t stream) {
    const float* image  = (const float*)d_in[0];
    const float* source = (const float*)d_in[1];
    const float* mask   = (const float*)d_in[2];
    const float* ybic   = (const float*)d_in[3];
    const float* logk   = (const float*)d_in[4];

    float* out_img = (float*)d_out;                          // [B,1,H,W]
    float* out_cv  = out_img + (size_t)BB * HH * WW;         // [B,1,H-1,W]
    float* out_ch  = out_cv + (size_t)BB * (HH - 1) * WW;    // [B,1,H,W-1]
    float* ws      = (float*)d_ws;                           // 4 MB ping buffer

    int total = BB * HH * WW;
    prep_kernel<<<(total + 255) / 256, 256, 0, stream>>>(image, ybic, logk, out_cv, out_ch);

    dim3 grid(WW / 64, HH / 64, BB);
    const float* cur = ybic;  // first launch reads y_bicubic directly
    for (int L = 0; L < NLAUNCH; ++L) {
        float* dst = (L % 2 == 0) ? ws : out_img;  // L=31 (odd) -> out_img
        multi_step_kernel<<<grid, 256, 0, stream>>>(cur, dst, out_cv, out_ch, source, mask);
        cur = dst;
    }
}